// Round 1
// baseline (1922.943 us; speedup 1.0000x reference)
//
#include <hip/hip_runtime.h>
#include <hip/hip_bf16.h>
#include <cstdint>
#include <cstddef>

typedef __attribute__((ext_vector_type(4))) float f32x4;
typedef __attribute__((ext_vector_type(8))) short short8;
typedef unsigned short u16;

#define SEQ     2048
#define BATCH   32
#define DIM     1024
#define N3      3072
#define SCHUNK  256
#define NCHUNK  8
#define MCH     (SCHUNK * BATCH)   /* 8192 rows per chunk GEMM */

// ---------------------------------------------------------------------------
// fp32 -> (hi,lo) bf16 split.  x = hi + lo + O(2^-18 |x|)
// ---------------------------------------------------------------------------
__device__ __forceinline__ u16 rne_bf16(float x) {
  unsigned u = __float_as_uint(x);
  return (u16)((u + 0x7FFFu + ((u >> 16) & 1u)) >> 16);
}

__global__ __launch_bounds__(256) void split_kernel(const float* __restrict__ src,
                                                    u16* __restrict__ hi,
                                                    u16* __restrict__ lo) {
  int t = blockIdx.x * 256 + threadIdx.x;          // one float4 per thread, exact grids
  float4 v = reinterpret_cast<const float4*>(src)[t];
  float xs[4] = {v.x, v.y, v.z, v.w};
  u16 hs[4], ls[4];
#pragma unroll
  for (int i = 0; i < 4; ++i) {
    u16 hb = rne_bf16(xs[i]);
    float hf = __uint_as_float((unsigned)hb << 16);
    hs[i] = hb;
    ls[i] = rne_bf16(xs[i] - hf);                  // exact residual, then RNE
  }
  ushort4 hv; hv.x = hs[0]; hv.y = hs[1]; hv.z = hs[2]; hv.w = hs[3];
  ushort4 lv; lv.x = ls[0]; lv.y = ls[1]; lv.z = ls[2]; lv.w = ls[3];
  reinterpret_cast<ushort4*>(hi)[t] = hv;
  reinterpret_cast<ushort4*>(lo)[t] = lv;
}

// ---------------------------------------------------------------------------
// async global->LDS, 16B per lane (dest = wave-uniform base + lane*16)
// ---------------------------------------------------------------------------
__device__ __forceinline__ void gload16(const void* g, void* l) {
  __builtin_amdgcn_global_load_lds(
      (const __attribute__((address_space(1))) void*)g,
      (__attribute__((address_space(3))) void*)l, 16, 0, 0);
}

// ---------------------------------------------------------------------------
// GEMM chunk: Yact[8192][3072] = act( Xc[8192][1024] * W[3072][1024]^T + b )
//   3-term bf16-split MFMA (hi*hi + lo*hi + hi*lo) ~ fp32 accuracy.
//   128x128 tile, BK=32, 4 waves (2x2 of 64x64), 16x16x32 bf16 MFMA.
//   LDS: 4 tiles [128 rows][32 bf16] with 16B-slot XOR swizzle
//        cell(row,q) holds data slot s = q ^ ((row>>1)&3)  (involution).
//   Staging: linear global_load_lds dest + pre-swizzled global source.
// ---------------------------------------------------------------------------
__global__ __launch_bounds__(256) void gemm_kernel(const u16* __restrict__ XhiC,
                                                   const u16* __restrict__ XloC,
                                                   const u16* __restrict__ Whi,
                                                   const u16* __restrict__ Wlo,
                                                   const float* __restrict__ bias,
                                                   float* __restrict__ Y) {
  __shared__ u16 lds[16384];                       // 4 x 8KB tiles = 32 KB
  const int tid  = threadIdx.x;
  const int lane = tid & 63;
  const int w    = tid >> 6;                       // wave 0..3
  const int wr   = w >> 1, wc = w & 1;             // 2x2 wave grid
  const int m0   = blockIdx.y * 128;               // chunk-local row base
  const int n0   = blockIdx.x * 128;               // output-feature base

  f32x4 acc[4][4] = {};

  // staging role: wave 0->Ahi, 1->Alo, 2->Bhi, 3->Blo (8 x 1KB wave-instrs each)
  const u16* src = (w == 0) ? XhiC : (w == 1) ? XloC : (w == 2) ? Whi : Wlo;
  const int rbase = (w < 2) ? m0 : n0;
  const int rr = lane >> 2;                        // row-in-16 within chunk
  const int sq = lane & 3;                         // linear 16B slot
  const int lr = lane & 15, lg = lane >> 4;

  for (int kt = 0; kt < 32; ++kt) {
    const int k0 = kt * 32;                        // k offset (bf16 elems)
#pragma unroll
    for (int c = 0; c < 8; ++c) {
      int r = c * 16 + rr;                         // tile row 0..127
      int s = sq ^ ((r >> 1) & 3);                 // data slot for this cell
      const u16* g = src + (size_t)(rbase + r) * 1024 + k0 + s * 8;
      gload16((const void*)g, (void*)&lds[w * 4096 + c * 512]);
    }
    __syncthreads();                               // drains vmcnt

    short8 ah[4], al[4], bh[4], bl[4];
#pragma unroll
    for (int i = 0; i < 4; ++i) {
      int row = wr * 64 + i * 16 + lr;
      int off = row * 32 + (lg ^ ((row >> 1) & 3)) * 8;
      ah[i] = *(const short8*)&lds[off];
      al[i] = *(const short8*)&lds[4096 + off];
    }
#pragma unroll
    for (int j = 0; j < 4; ++j) {
      int row = wc * 64 + j * 16 + lr;
      int off = row * 32 + (lg ^ ((row >> 1) & 3)) * 8;
      bh[j] = *(const short8*)&lds[8192 + off];
      bl[j] = *(const short8*)&lds[12288 + off];
    }
#pragma unroll
    for (int i = 0; i < 4; ++i)
#pragma unroll
      for (int j = 0; j < 4; ++j) {
        acc[i][j] = __builtin_amdgcn_mfma_f32_16x16x32_bf16(ah[i], bh[j], acc[i][j], 0, 0, 0);
        acc[i][j] = __builtin_amdgcn_mfma_f32_16x16x32_bf16(al[i], bh[j], acc[i][j], 0, 0, 0);
        acc[i][j] = __builtin_amdgcn_mfma_f32_16x16x32_bf16(ah[i], bl[j], acc[i][j], 0, 0, 0);
      }
    __syncthreads();
  }

  // epilogue: bias + activation (block is entirely within one gate: 1024%128==0)
  const int gate = n0 >> 10;                       // 0:Z(tanh) 1:F(sigm) 2:O(sigm)
#pragma unroll
  for (int j = 0; j < 4; ++j) {
    int n = n0 + wc * 64 + j * 16 + lr;
    float bv = bias[n];
#pragma unroll
    for (int i = 0; i < 4; ++i) {
      int rowb = m0 + wr * 64 + i * 16 + lg * 4;   // C/D: row=(lane>>4)*4+r, col=lane&15
#pragma unroll
      for (int r = 0; r < 4; ++r) {
        float v = acc[i][j][r] + bv;
        float a;
        if (gate == 0) { float e = __expf(2.f * v); a = 1.f - 2.f / (e + 1.f); }   // tanh
        else           { a = 1.f / (1.f + __expf(-v)); }                            // sigmoid
        Y[(size_t)(rowb + r) * N3 + n] = a;
      }
    }
  }
}

// ---------------------------------------------------------------------------
// Scan chunk: one thread per (b,d) chain; h = f*h + (1-f)*z; H = sig(O)*h
// ---------------------------------------------------------------------------
__global__ __launch_bounds__(64) void scan_kernel(const float* __restrict__ Y,
                                                  const float* __restrict__ hin,
                                                  float* __restrict__ hout,
                                                  float* __restrict__ H,
                                                  float* __restrict__ hn,
                                                  int write_hn) {
  int t = blockIdx.x * 64 + threadIdx.x;           // 0..32767 ; t = b*1024 + d
  int b = t >> 10, d = t & 1023;
  float h = hin[t];
  size_t o  = (size_t)b * N3 + d;                  // Y[(s*32+b)*3072 + gate*1024 + d]
  size_t oh = (size_t)t;                           // H[(s*32+b)*1024 + d]
#pragma unroll 8
  for (int s = 0; s < SCHUNK; ++s) {
    float z = Y[o];
    float f = Y[o + 1024];
    float g = Y[o + 2048];
    h = fmaf(f, h - z, z);                         // f*h + (1-f)*z
    H[oh] = g * h;
    o  += (size_t)BATCH * N3;                      // next s
    oh += (size_t)BATCH * DIM;
  }
  hout[t] = h;
  if (write_hn) hn[t] = h;
}

// ---------------------------------------------------------------------------
extern "C" void kernel_launch(void* const* d_in, const int* in_sizes, int n_in,
                              void* d_out, int out_size, void* d_ws, size_t ws_size,
                              hipStream_t stream) {
  const float* X      = (const float*)d_in[0];     // (2048,32,1024)
  const float* hidden = (const float*)d_in[1];     // (1,32,1024)
  const float* W      = (const float*)d_in[2];     // (3072,1024)
  const float* bias   = (const float*)d_in[3];     // (3072,)
  float* Hout = (float*)d_out;                     // 67,108,864 floats
  float* hn   = Hout + (size_t)SEQ * BATCH * DIM;  // + 32,768 floats

  // workspace layout (bytes)
  char* ws = (char*)d_ws;
  u16*   Whi    = (u16*)(ws);                          // 6,291,456 B
  u16*   Wlo    = (u16*)(ws + 6291456);                // 6,291,456 B
  u16*   Xhi    = (u16*)(ws + 12582912);               // 16,777,216 B
  u16*   Xlo    = (u16*)(ws + 29360128);               // 16,777,216 B
  float* Yc     = (float*)(ws + 46137344);             // 100,663,296 B
  float* hstate = (float*)(ws + 146800640);            // 131,072 B  -> 146,931,712 total
  if (ws_size < 146931712u) return;                    // clean fail if ws too small

  // W -> hi/lo bf16 (3,145,728 floats = 786,432 float4 = 3072 blocks)
  split_kernel<<<3072, 256, 0, stream>>>(W, Whi, Wlo);

  for (int c = 0; c < NCHUNK; ++c) {
    const size_t xoff = (size_t)c * MCH * DIM;         // floats
    // X chunk -> hi/lo (8,388,608 floats = 2,097,152 float4 = 8192 blocks)
    split_kernel<<<8192, 256, 0, stream>>>(X + xoff, Xhi, Xlo);
    // chunk GEMM + activations
    dim3 g(N3 / 128, MCH / 128);                       // (24, 64)
    gemm_kernel<<<g, 256, 0, stream>>>(Xhi, Xlo, Whi, Wlo, bias, Yc);
    // chunk scan (h carried through hstate; chunk 0 seeds from `hidden`)
    scan_kernel<<<512, 64, 0, stream>>>(Yc,
                                        (c == 0) ? hidden : hstate,
                                        hstate,
                                        Hout + xoff,
                                        hn,
                                        (c == NCHUNK - 1) ? 1 : 0);
  }
}